// Round 10
// baseline (837.105 us; speedup 1.0000x reference)
//
#include <hip/hip_runtime.h>

// ---------------- problem constants ----------------
#define NNODES 8192
#define NEDGES 262144
#define CCH    128          // sphere channels (C = EC = 128)
#define HCH    512          // hidden channels
#define GCOLS  6144         // 2*2560 (eq gates) + 2*512 (ne gates)
#define ROWS   204800       // N * M = 8192 * 25
#define XSPAD  136          // gate-gemm LDS row stride (bf16 elems)

typedef __bf16 bf16_t;
typedef __bf16 bf16x8 __attribute__((ext_vector_type(8)));
typedef __bf16 bf16x4 __attribute__((ext_vector_type(4)));
typedef float  f32x4  __attribute__((ext_vector_type(4)));

// silu via fast rcp (v_rcp_f32, ~1 ulp): 5 VALU ops vs ~10 for default fdiv
__device__ __forceinline__ float siluf(float x) {
  return x * __builtin_amdgcn_rcpf(1.f + __expf(-x));
}

#define GLOAD_LDS(g, l) __builtin_amdgcn_global_load_lds( \
    (const __attribute__((address_space(1))) void*)(g), \
    (__attribute__((address_space(3))) void*)(l), 16, 0, 0)

// ---------------- workspace layout (bytes) ----------------
constexpr size_t OFF_CSUM  = 0;           // 8192*128 f32 (mean, router input)
constexpr size_t OFF_DEG   = 4194304;     // 8192 i32
constexpr size_t OFF_OFFS  = 4227072;     // 8193 i32 (padded)
constexpr size_t OFF_CUR   = 4263936;     // 8192 i32
constexpr size_t OFF_EIDS  = 4296704;     // 262144 i32
constexpr size_t OFF_WRT   = 5345280;     // 8192*4 f32
constexpr size_t OFF_CBF   = 5476352;     // 8192*128 bf16
constexpr size_t OFF_WPT   = 7573504;     // 6144*128 bf16
constexpr size_t OFF_BPK   = 9146368;     // 6144 f32
constexpr size_t OFF_W1T   = 9170944;     // 4*512*128 bf16 (32h-chunked rows)
constexpr size_t OFF_W2T   = 9695232;     // 4*16*128*32 bf16 (32k-chunked)
constexpr size_t OFF_GATES = 10219520;    // chunk*6144 bf16 (adaptive)

// ---------------- kernel 1a: per-node degree count ----------------
__global__ __launch_bounds__(256) void edge_count_kernel(
    const int* __restrict__ edge_index, int* __restrict__ deg)
{
  int e = blockIdx.x * 256 + threadIdx.x;
  int dst = __builtin_nontemporal_load(&edge_index[NEDGES + e]);
  atomicAdd(&deg[dst], 1);
}

// ---------------- kernel 1b: exclusive scan (single block) ----------------
__global__ __launch_bounds__(256) void scan_kernel(
    const int* __restrict__ deg, int* __restrict__ offs, int* __restrict__ cur)
{
  __shared__ int part[256];
  int t = threadIdx.x;
  int s = 0;
  #pragma unroll 4
  for (int i = 0; i < 32; ++i) s += deg[t * 32 + i];
  part[t] = s;
  __syncthreads();
  int incl = s;
  for (int off = 1; off < 256; off <<= 1) {
    int u = (t >= off) ? part[t - off] : 0;
    __syncthreads();
    incl += u;
    part[t] = incl;
    __syncthreads();
  }
  int run = incl - s;      // exclusive prefix of this thread's 32-chunk
  for (int i = 0; i < 32; ++i) {
    int d = deg[t * 32 + i];
    offs[t * 32 + i] = run;
    cur[t * 32 + i]  = run;
    run += d;
  }
  if (t == 255) offs[8192] = run;   // == NEDGES
}

// ---------------- kernel 1c: fill CSR edge-id slots ----------------
__global__ __launch_bounds__(256) void edge_fill_kernel(
    const int* __restrict__ edge_index, int* __restrict__ cur, int* __restrict__ eids)
{
  int e = blockIdx.x * 256 + threadIdx.x;
  int dst = __builtin_nontemporal_load(&edge_index[NEDGES + e]);
  int pos = atomicAdd(&cur[dst], 1);
  eids[pos] = e;
}

// ---------------- kernel 1d: gather + mean (8-way edge-parallel, f32x4 NT) ----------------
__global__ __launch_bounds__(256) void gather_mean_kernel(
    const float* __restrict__ t_ij, const int* __restrict__ offs,
    const int* __restrict__ eids, float* __restrict__ csum, bf16_t* __restrict__ cbf)
{
  __shared__ float red[8][128];
  int n = blockIdx.x, tid = threadIdx.x;
  int sub = tid & 31, rp = tid >> 5;           // 8 groups x 32 lanes (16 B each)
  int o0 = offs[n], o1 = offs[n + 1];
  f32x4 acc = {0.f, 0.f, 0.f, 0.f};
  for (int j = o0 + rp; j < o1; j += 8) {
    int e = __builtin_nontemporal_load(&eids[j]);
    f32x4 v = __builtin_nontemporal_load((const f32x4*)&t_ij[(size_t)e * CCH + sub * 4]);
    #pragma unroll
    for (int q = 0; q < 4; ++q) acc[q] += v[q];
  }
  *(f32x4*)&red[rp][sub * 4] = acc;
  __syncthreads();
  if (rp == 0) {
    float inv = 1.f / fmaxf((float)(o1 - o0), 1.f);
    f32x4 s = {0.f, 0.f, 0.f, 0.f};
    #pragma unroll
    for (int k = 0; k < 8; ++k) {
      f32x4 r = *(const f32x4*)&red[k][sub * 4];
      #pragma unroll
      for (int q = 0; q < 4; ++q) s[q] += r[q];
    }
    f32x4 m;
    bf16x4 mb;
    #pragma unroll
    for (int q = 0; q < 4; ++q) { m[q] = s[q] * inv; mb[q] = (bf16_t)m[q]; }
    *(f32x4*)&csum[(size_t)n * CCH + sub * 4] = m;
    *(bf16x4*)&cbf[(size_t)n * CCH + sub * 4] = mb;
  }
}

// ---------------- kernel 3: pack weights via LDS 32x32 tiled transpose ----------------
__global__ __launch_bounds__(256) void pack_kernel(
    const float* __restrict__ eq_gate_w, const float* __restrict__ ne_gate_w,
    const float* __restrict__ eq_gate_b, const float* __restrict__ ne_gate_b,
    const float* __restrict__ eq_w1, const float* __restrict__ ne_w1,
    const float* __restrict__ eq_w2, const float* __restrict__ ne_w2,
    bf16_t* __restrict__ WpackT, float* __restrict__ bpack,
    bf16_t* __restrict__ w1T, bf16_t* __restrict__ w2c)
{
  __shared__ float tb[32][33];
  int b = blockIdx.x;
  int tid = threadIdx.x, tx = tid & 31, ty = tid >> 5;   // 32 x 8
  if (b == 1280) {                                       // biases (contiguous)
    #pragma unroll
    for (int it = 0; it < 24; ++it) {
      int j = it * 256 + tid;
      bpack[j] = (j < 5120) ? eq_gate_b[j] : ne_gate_b[j - 5120];
    }
    return;
  }
  const float* src; bf16_t* dst; int stride; bool w2mode = false;
  int c0, h0; size_t dbase;
  if (b < 640) {                       // WpackT eq: [2][128c][2560h] -> [j=e*2560+h][c]
    int e = b / 320, r = b % 320, ct = r / 80, ht = r % 80;
    src = eq_gate_w + (size_t)e * 327680; stride = 2560;
    c0 = ct * 32; h0 = ht * 32;
    dbase = ((size_t)e * 2560 + h0) * 128 + c0; dst = WpackT;
  } else if (b < 768) {                // WpackT ne: [2][128c][512h] -> [5120+e*512+h][c]
    int bb = b - 640, e = bb / 64, r = bb % 64, ct = r / 16, ht = r % 16;
    src = ne_gate_w + (size_t)e * 65536; stride = 512;
    c0 = ct * 32; h0 = ht * 32;
    dbase = ((size_t)(5120 + e * 512) + h0) * 128 + c0; dst = WpackT;
  } else if (b < 1024) {               // w1T: [e][128c][512h] -> [e*512+h][c]
    int bb = b - 768, e = bb / 64, r = bb % 64, ct = r / 16, ht = r % 16;
    src = (e < 2) ? eq_w1 + (size_t)e * 65536 : ne_w1 + (size_t)(e - 2) * 65536;
    stride = 512;
    c0 = ct * 32; h0 = ht * 32;
    dbase = ((size_t)(e * 512) + h0) * 128 + c0; dst = w1T;
  } else {                             // w2c: [e][512h][128c] -> [e][h>>5][c][h&31]
    int bb = b - 1024, e = bb / 64, r = bb % 64, ht = r / 4, ct = r % 4;
    src = (e < 2) ? eq_w2 + (size_t)e * 65536 : ne_w2 + (size_t)(e - 2) * 65536;
    stride = 128; w2mode = true;
    c0 = ct * 32; h0 = ht * 32;
    dbase = (size_t)e * 65536 + (size_t)ht * 4096 + (size_t)c0 * 32;
    dst = w2c;
  }
  if (!w2mode) {
    #pragma unroll
    for (int p = 0; p < 4; ++p)        // tb[c'][h'], coalesced src rows (c-major)
      tb[p * 8 + ty][tx] = src[(size_t)(c0 + p * 8 + ty) * stride + h0 + tx];
    __syncthreads();
    #pragma unroll
    for (int p = 0; p < 4; ++p)        // row h, cols c contiguous
      dst[dbase + (size_t)(p * 8 + ty) * 128 + tx] = (bf16_t)tb[tx][p * 8 + ty];
  } else {
    #pragma unroll
    for (int p = 0; p < 4; ++p)        // tb[h'][c'], coalesced src rows (h-major)
      tb[p * 8 + ty][tx] = src[(size_t)(h0 + p * 8 + ty) * 128 + c0 + tx];
    __syncthreads();
    #pragma unroll
    for (int p = 0; p < 4; ++p)        // row c (32-h chunk), cols h contiguous
      dst[dbase + (size_t)(p * 8 + ty) * 32 + tx] = (bf16_t)tb[tx][p * 8 + ty];
  }
}

// ---------------- kernel 4: router (all fp32) ----------------
__global__ __launch_bounds__(128) void router_kernel(
    const float* __restrict__ c,
    const float* __restrict__ r_w1, const float* __restrict__ r_b1,
    const float* __restrict__ r_w2, const float* __restrict__ r_b2,
    float* __restrict__ wroute)
{
  __shared__ float cl[128];
  __shared__ float h1[128];
  __shared__ float lg[4];
  int n = blockIdx.x, tid = threadIdx.x;
  cl[tid] = c[(size_t)n * 128 + tid];
  __syncthreads();
  float a = 0.f;
  #pragma unroll 8
  for (int k = 0; k < 128; ++k) a += cl[k] * r_w1[k * 128 + tid];
  a += r_b1[tid];
  h1[tid] = siluf(a);
  __syncthreads();
  if (tid < 4) {
    float s = 0.f;
    for (int j = 0; j < 128; ++j) s += h1[j] * r_w2[j * 4 + tid];
    lg[tid] = s + r_b2[tid];
  }
  __syncthreads();
  if (tid == 0) {
    float m = fmaxf(fmaxf(lg[0], lg[1]), fmaxf(lg[2], lg[3]));
    float e0 = __expf(lg[0] - m), e1 = __expf(lg[1] - m);
    float e2 = __expf(lg[2] - m), e3 = __expf(lg[3] - m);
    float s = 1.f / (e0 + e1 + e2 + e3);
    f32x4 w = {e0 * s, e1 * s, e2 * s, e3 * s};
    *(f32x4*)&wroute[n * 4] = w;
  }
}

// ---------------- kernel 5: gate GEMM ----------------
// gates[n][p] = silu(c@Wpack + b) * wroute[n][e(j)], stored PERMUTED within each
// 64-col chunk: logical j = tr*16 + quad*4 + q  ->  p = quad*16 + tr*4 + q.
// NOTE: no 2nd launch_bounds arg — on this toolchain it CAPS waves/EU (R9 finding).
__global__ __launch_bounds__(256) void gate_gemm_kernel(
    const bf16_t* __restrict__ WpackT, const bf16_t* __restrict__ cbf,
    const float* __restrict__ bpack, const float* __restrict__ wroute,
    bf16_t* __restrict__ gates, int n0)
{
  __shared__ bf16_t gt[128 * XSPAD];
  int jt = blockIdx.x, nt = blockIdx.y;
  int tid = threadIdx.x;
  int wave = tid >> 6, lane = tid & 63;
  int wr = wave >> 1, wc = wave & 1;
  int l15 = lane & 15, quad = lane >> 4;
  int ej = (jt < 20) ? 0 : (jt < 40) ? 1 : (jt < 44) ? 2 : 3;

  f32x4 acc[4][4];
  #pragma unroll
  for (int i = 0; i < 4; ++i)
    #pragma unroll
    for (int j = 0; j < 4; ++j) acc[i][j] = {0.f, 0.f, 0.f, 0.f};

  const bf16_t* abase = WpackT + ((size_t)jt * 128 + wr * 64 + l15) * 128 + quad * 8;
  const bf16_t* bbase = cbf + ((size_t)(n0 + nt * 128) + wc * 64 + l15) * 128 + quad * 8;
  float wsc[4];
  #pragma unroll
  for (int tc = 0; tc < 4; ++tc)
    wsc[tc] = wroute[(size_t)(n0 + nt * 128 + wc * 64 + tc * 16 + l15) * 4 + ej];
  #pragma unroll
  for (int ks = 0; ks < 4; ++ks) {
    bf16x8 af[4], bfr[4];
    #pragma unroll
    for (int tr = 0; tr < 4; ++tr) af[tr] = *(const bf16x8*)(abase + (size_t)tr * 16 * 128 + ks * 32);
    #pragma unroll
    for (int tc = 0; tc < 4; ++tc) bfr[tc] = *(const bf16x8*)(bbase + (size_t)tc * 16 * 128 + ks * 32);
    #pragma unroll
    for (int tr = 0; tr < 4; ++tr)
      #pragma unroll
      for (int tc = 0; tc < 4; ++tc)
        acc[tr][tc] = __builtin_amdgcn_mfma_f32_16x16x32_bf16(af[tr], bfr[tc], acc[tr][tc], 0, 0, 0);
  }
  #pragma unroll
  for (int tr = 0; tr < 4; ++tr) {
    int j0 = wr * 64 + tr * 16 + quad * 4;       // logical col (for bias values)
    int p0 = wr * 64 + quad * 16 + tr * 4;       // permuted store position
    f32x4 bb = *(const f32x4*)&bpack[jt * 128 + j0];
    #pragma unroll
    for (int tc = 0; tc < 4; ++tc) {
      int nl = wc * 64 + tc * 16 + l15;
      f32x4 v = acc[tr][tc];
      bf16x4 gv;
      #pragma unroll
      for (int q = 0; q < 4; ++q) gv[q] = (bf16_t)(siluf(v[q] + bb[q]) * wsc[tc]);
      *(bf16x4*)&gt[nl * XSPAD + p0] = gv;
    }
  }
  __syncthreads();
  #pragma unroll
  for (int it = 0; it < 8; ++it) {
    int idx = it * 2048 + tid * 8;
    int lr = idx >> 7, col = idx & 127;
    *(bf16x8*)&gates[((size_t)nt * 128 + lr) * GCOLS + jt * 128 + col] =
        *(const bf16x8*)&gt[lr * XSPAD + col];
  }
}

// ---------------- kernel 6: fused experts (256 thr, 24 KB LDS, uncapped occupancy) ----------------
// R9 finding: __launch_bounds__ 2nd arg acts as a waves/EU CAP on this toolchain
// (Occ% tracked the arg across 9 rounds, never the LDS). Drop it -> occupancy
// floats to resource limit: VGPR ~88 -> 5 waves/SIMD; LDS 24 KB -> ~4-5 blocks/CU.
// Also fix R9's ws2 8-way bank conflict (64-B rows, no swizzle was WRONG:
// different rows in same banks serialize). XOR byte ^= ((row>>1)&3)<<4 on both
// staging source and read side (read row = l15+tr*16 -> XOR = ((l15>>1)&3)<<4).
__global__ __launch_bounds__(256) void fused_experts_kernel(
    const float* __restrict__ x,       // [204800][128] fp32
    const bf16_t* __restrict__ w1T,    // [4][512][128]; 32h chunk = 4096 elems
    const bf16_t* __restrict__ w2c,    // [4][16][128][32]; chunk = 4096 elems
    const bf16_t* __restrict__ gates,  // [chunk][6144], pre-scaled, 64-chunk-permuted
    const float* __restrict__ wroute,  // [8192][4]
    const float* __restrict__ ne_b1,   // [2][512] fp32
    const float* __restrict__ ne_b2,   // [2][128] fp32
    float* __restrict__ out,           // [204800][128] fp32
    int n0)
{
  __shared__ __align__(16) bf16_t ws1[4096];          // 8 KB: 32h x 128k (swizzled)
  __shared__ __align__(16) bf16_t ws2[4096];          // 8 KB: 128c x 32k (swizzled)
  __shared__ __align__(16) bf16_t hg[4 * 32 * 32];    // 8 KB, XOR-swizzled rows

  const int tid = threadIdx.x;
  const int wave = tid >> 6, lane = tid & 63;
  const int l15 = lane & 15, quad = lane >> 4;
  const int r0 = n0 * 25 + blockIdx.x * 128;
  const int rbase = wave * 32;
  char* hgw = (char*)(hg + wave * 32 * 32);           // 2 KB/wave, 64-B rows

  // staging: 256 threads x 2 x 16 B per buffer = 8 KB each.
  // ws1 source pre-swizzled (byte ^= (row&7)<<4, 256-B rows);
  // ws2 source pre-swizzled (byte ^= ((row>>1)&3)<<4, 64-B rows).
  int soff1[2], soff2[2];
  #pragma unroll
  for (int i = 0; i < 2; ++i) {
    int p = wave * 2048 + i * 1024 + lane * 16;
    int row1 = p >> 8;                         // w1: 32 rows x 256 B
    soff1[i] = (row1 * 256 + ((p & 255) ^ ((row1 & 7) << 4))) >> 1;
    int row2 = p >> 6;                         // w2: 128 rows x 64 B
    soff2[i] = (row2 * 64 + ((p & 63) ^ (((row2 >> 1) & 3) << 4))) >> 1;
  }
  const int swz = (l15 & 7) << 4;              // ws1 read-side XOR
  int colswz[4];
  #pragma unroll
  for (int ks = 0; ks < 4; ++ks) colswz[ks] = (ks * 64 + quad * 16) ^ swz;
  const int w2swz = ((l15 >> 1) & 3) << 4;     // ws2 read-side XOR (tr-independent)
  const int hswz = (l15 & 3) << 4;             // hg XOR (both sides)

  // per-lane row metadata + x panel into registers (non-temporal: read-once)
  int nloc[2], lidx[2];
  f32x4 rw[2];
  bf16x8 xf[2][4];
  #pragma unroll
  for (int tc = 0; tc < 2; ++tc) {
    int r = r0 + rbase + tc * 16 + l15;
    int n = r / 25;
    int m = r - n * 25;
    nloc[tc] = n - n0;
    lidx[tc] = (m == 0) ? 0 : (m < 4) ? 1 : (m < 9) ? 2 : (m < 16) ? 3 : 4;
    rw[tc] = *(const f32x4*)&wroute[n * 4];
    const float* xr = x + (size_t)r * CCH + quad * 8;
    #pragma unroll
    for (int ks = 0; ks < 4; ++ks) {
      f32x4 a = __builtin_nontemporal_load((const f32x4*)(xr + ks * 32));
      f32x4 b = __builtin_nontemporal_load((const f32x4*)(xr + ks * 32 + 4));
      bf16x8 v;
      #pragma unroll
      for (int q = 0; q < 4; ++q) { v[q] = (bf16_t)a[q]; v[4 + q] = (bf16_t)b[q]; }
      xf[tc][ks] = v;
    }
  }

  // gates address for iter tt = (e, hh): permuted 64-chunk => the 8 values this
  // lane needs (h = hh*32 + tr*16 + quad*4 + q) are ONE contiguous bf16x8 at
  // chunkbase + quad*16 + (hh&1)*8.
  auto gaddr = [&](int tc, int tt) -> const bf16_t* {
    int ee = tt >> 4, hh = tt & 15;
    int base = (ee < 2) ? ee * 2560 + lidx[tc] * 512 : 5120 + (ee - 2) * 512;
    return gates + (nloc[tc] * GCOLS + base + (hh >> 1) * 64 + (hh & 1) * 8 + quad * 16);
  };

  f32x4 oacc[8][2];
  #pragma unroll
  for (int i = 0; i < 8; ++i)
    #pragma unroll
    for (int j = 0; j < 2; ++j) oacc[i][j] = {0.f, 0.f, 0.f, 0.f};

  // prologue: gates(0) prefetch
  bf16x8 gnx[2];
  #pragma unroll
  for (int tc = 0; tc < 2; ++tc) gnx[tc] = *(const bf16x8*)gaddr(tc, 0);

  #pragma unroll 1
  for (int t = 0; t < 64; ++t) {
    const int e = t >> 4, hh = t & 15;
    const bool is_eq = (e < 2);

    // ---- stage chunk t (both buffers) ----
    const bf16_t* g1 = w1T + ((size_t)t << 12);
    const bf16_t* g2 = w2c + ((size_t)t << 12);
    #pragma unroll
    for (int i = 0; i < 2; ++i) {
      GLOAD_LDS(g1 + soff1[i], ws1 + wave * 1024 + i * 512);
      GLOAD_LDS(g2 + soff2[i], ws2 + wave * 1024 + i * 512);
    }
    __syncthreads();   // staging visible (prev-iter reads were fenced by end sync)

    // ---- consume prefetched gates; issue next iter's ----
    bf16x8 ga[2];
    #pragma unroll
    for (int tc = 0; tc < 2; ++tc) ga[tc] = gnx[tc];
    if (t < 63) {
      #pragma unroll
      for (int tc = 0; tc < 2; ++tc) gnx[tc] = *(const bf16x8*)gaddr(tc, t + 1);
    }

    // ---- GEMM1: hacc[h(2x16)][r(2x16)], K=128, A from ws1 ----
    f32x4 hacc[2][2];
    #pragma unroll
    for (int i = 0; i < 2; ++i)
      #pragma unroll
      for (int j = 0; j < 2; ++j) hacc[i][j] = {0.f, 0.f, 0.f, 0.f};
    #pragma unroll
    for (int ks = 0; ks < 4; ++ks) {
      bf16x8 af[2];
      #pragma unroll
      for (int tr = 0; tr < 2; ++tr)
        af[tr] = *(const bf16x8*)((const char*)ws1 + (l15 + tr * 16) * 256 + colswz[ks]);
      #pragma unroll
      for (int tr = 0; tr < 2; ++tr)
        #pragma unroll
        for (int tc = 0; tc < 2; ++tc)
          hacc[tr][tc] = __builtin_amdgcn_mfma_f32_16x16x32_bf16(af[tr], xf[tc][ks], hacc[tr][tc], 0, 0, 0);
    }
    // ---- gating + hg write (rows 64 B, byte ^= hswz) ----
    #pragma unroll
    for (int tc = 0; tc < 2; ++tc) {
      #pragma unroll
      for (int tr = 0; tr < 2; ++tr) {
        int hl = tr * 16 + quad * 4;           // h within 32-chunk
        f32x4 v = hacc[tr][tc];
        if (is_eq) {
          if (lidx[tc] == 0) {
            #pragma unroll
            for (int q = 0; q < 4; ++q) v[q] = siluf(v[q]);
          }
        } else {
          f32x4 b1 = *(const f32x4*)&ne_b1[(e - 2) * 512 + hh * 32 + hl];
          #pragma unroll
          for (int q = 0; q < 4; ++q) v[q] = siluf(v[q] + b1[q]);
        }
        bf16x4 hv;
        #pragma unroll
        for (int q = 0; q < 4; ++q) {
          float gf = (float)ga[tc][tr * 4 + q];
          hv[q] = (bf16_t)(v[q] * gf);
        }
        *(bf16x4*)(hgw + (tc * 16 + l15) * 64 + ((tr * 32 + quad * 8) ^ hswz)) = hv;
      }
    }
    __builtin_amdgcn_wave_barrier();   // intra-wave hg write -> read order
    // ---- GEMM2: oacc[c(8x16)][r(2x16)] += ws2 * hg, K=32 ----
    bf16x8 bfr[2];
    #pragma unroll
    for (int tc = 0; tc < 2; ++tc)
      bfr[tc] = *(const bf16x8*)(hgw + (tc * 16 + l15) * 64 + ((quad * 16) ^ hswz));
    #pragma unroll
    for (int tr = 0; tr < 8; ++tr) {
      bf16x8 af2 = *(const bf16x8*)((const char*)ws2 + (l15 + tr * 16) * 64 + ((quad * 16) ^ w2swz));
      #pragma unroll
      for (int tc = 0; tc < 2; ++tc)
        oacc[tr][tc] = __builtin_amdgcn_mfma_f32_16x16x32_bf16(af2, bfr[tc], oacc[tr][tc], 0, 0, 0);
    }
    __syncthreads();   // all ws1/ws2 reads done before next stage overwrites
  }
  // ---- epilogue: out[r][c] = oacc + w_ne*b2 terms (NT fp32 store) ----
  #pragma unroll
  for (int tc = 0; tc < 2; ++tc) {
    size_t rg = (size_t)(r0 + rbase + tc * 16 + l15);
    float wn0 = rw[tc][2], wn1 = rw[tc][3];
    #pragma unroll
    for (int tr = 0; tr < 8; ++tr) {
      int c0 = tr * 16 + quad * 4;
      f32x4 v = oacc[tr][tc];
      f32x4 b20 = *(const f32x4*)&ne_b2[c0];
      f32x4 b21 = *(const f32x4*)&ne_b2[128 + c0];
      f32x4 ov;
      #pragma unroll
      for (int q = 0; q < 4; ++q)
        ov[q] = v[q] + wn0 * b20[q] + wn1 * b21[q];
      __builtin_nontemporal_store(ov, (f32x4*)&out[rg * CCH + c0]);
    }
  }
}

// ---------------- launch ----------------
extern "C" void kernel_launch(void* const* d_in, const int* in_sizes, int n_in,
                              void* d_out, int out_size, void* d_ws, size_t ws_size,
                              hipStream_t stream)
{
  const float* x_emb     = (const float*)d_in[0];
  const float* t_ij      = (const float*)d_in[1];
  const int*   edge_index= (const int*)d_in[2];
  const float* eq_w1     = (const float*)d_in[3];
  const float* eq_gate_w = (const float*)d_in[4];
  const float* eq_gate_b = (const float*)d_in[5];
  const float* eq_w2     = (const float*)d_in[6];
  const float* ne_w1     = (const float*)d_in[7];
  const float* ne_b1     = (const float*)d_in[8];
  const float* ne_gate_w = (const float*)d_in[9];
  const float* ne_gate_b = (const float*)d_in[10];
  const float* ne_w2     = (const float*)d_in[11];
  const float* ne_b2     = (const float*)d_in[12];
  const float* r_w1      = (const float*)d_in[13];
  const float* r_b1      = (const float*)d_in[14];
  const float* r_w2      = (const float*)d_in[15];
  const float* r_b2      = (const float*)d_in[16];
  float* out = (float*)d_out;

  char* ws = (char*)d_ws;
  float*  csum   = (float*)(ws + OFF_CSUM);
  int*    deg    = (int*)(ws + OFF_DEG);
  int*    offs   = (int*)(ws + OFF_OFFS);
  int*    cur    = (int*)(ws + OFF_CUR);
  int*    eids   = (int*)(ws + OFF_EIDS);
  float*  wroute = (float*)(ws + OFF_WRT);
  bf16_t* cbf    = (bf16_t*)(ws + OFF_CBF);
  bf16_t* WpackT = (bf16_t*)(ws + OFF_WPT);
  float*  bpack  = (float*)(ws + OFF_BPK);
  bf16_t* w1T    = (bf16_t*)(ws + OFF_W1T);
  bf16_t* w2c    = (bf16_t*)(ws + OFF_W2T);
  bf16_t* gates  = (bf16_t*)(ws + OFF_GATES);

  // Adaptive node-chunking for the gates buffer (ws_size constant across calls).
  // chunk multiple of 128 so chunk*25/128 (fused grid) is integral.
  size_t avail = (ws_size > OFF_GATES) ? ws_size - OFF_GATES : 0;
  int chunk = 128;
  for (int c = NNODES; c >= 128; c >>= 1) {
    if ((size_t)c * GCOLS * sizeof(bf16_t) <= avail) { chunk = c; break; }
  }

  hipMemsetAsync(ws + OFF_DEG, 0, 32768, stream);   // zero deg only

  // CSR build + gather-mean
  edge_count_kernel<<<NEDGES / 256, 256, 0, stream>>>(edge_index, deg);
  scan_kernel<<<1, 256, 0, stream>>>(deg, offs, cur);
  edge_fill_kernel<<<NEDGES / 256, 256, 0, stream>>>(edge_index, cur, eids);
  gather_mean_kernel<<<NNODES, 256, 0, stream>>>(t_ij, offs, eids, csum, cbf);

  pack_kernel<<<1281, 256, 0, stream>>>(eq_gate_w, ne_gate_w, eq_gate_b, ne_gate_b,
                                        eq_w1, ne_w1, eq_w2, ne_w2,
                                        WpackT, bpack, w1T, w2c);
  router_kernel<<<NNODES, 128, 0, stream>>>(csum, r_w1, r_b1, r_w2, r_b2, wroute);

  for (int n0 = 0; n0 < NNODES; n0 += chunk) {
    gate_gemm_kernel<<<dim3(GCOLS / 128, chunk / 128), 256, 0, stream>>>(
        WpackT, cbf, bpack, wroute, gates, n0);
    fused_experts_kernel<<<chunk * 25 / 128, 256, 0, stream>>>(
        x_emb, w1T, w2c, gates, wroute, ne_b1, ne_b2, out, n0);
  }
}

// Round 11
// 766.084 us; speedup vs baseline: 1.0927x; 1.0927x over previous
//
#include <hip/hip_runtime.h>

// ---------------- problem constants ----------------
#define NNODES 8192
#define NEDGES 262144
#define CCH    128          // sphere channels (C = EC = 128)
#define HCH    512          // hidden channels
#define GCOLS  6144         // 2*2560 (eq gates) + 2*512 (ne gates)
#define ROWS   204800       // N * M = 8192 * 25
#define XSPAD  136          // gate-gemm LDS row stride (bf16 elems)
#define HGPAD  72           // hg LDS row stride

typedef __bf16 bf16_t;
typedef __bf16 bf16x8 __attribute__((ext_vector_type(8)));
typedef __bf16 bf16x4 __attribute__((ext_vector_type(4)));
typedef float  f32x4  __attribute__((ext_vector_type(4)));

// silu via fast rcp (v_rcp_f32, ~1 ulp): 5 VALU ops vs ~10 for default fdiv
__device__ __forceinline__ float siluf(float x) {
  return x * __builtin_amdgcn_rcpf(1.f + __expf(-x));
}

#define GLOAD_LDS(g, l) __builtin_amdgcn_global_load_lds( \
    (const __attribute__((address_space(1))) void*)(g), \
    (__attribute__((address_space(3))) void*)(l), 16, 0, 0)

// ---------------- workspace layout (bytes) ----------------
constexpr size_t OFF_CSUM  = 0;           // (unused now; kept for layout stability)
constexpr size_t OFF_DEG   = 4194304;     // 8192 i32
constexpr size_t OFF_OFFS  = 4227072;     // 8193 i32 (padded)
constexpr size_t OFF_CUR   = 4263936;     // 8192 i32
constexpr size_t OFF_EIDS  = 4296704;     // 262144 i32
constexpr size_t OFF_WRT   = 5345280;     // 8192*4 f32
constexpr size_t OFF_CBF   = 5476352;     // 8192*128 bf16
constexpr size_t OFF_WPT   = 7573504;     // 6144*128 bf16
constexpr size_t OFF_BPK   = 9146368;     // 6144 f32
constexpr size_t OFF_W1T   = 9170944;     // 4*512*128 bf16 ((e,hc)-chunked rows)
constexpr size_t OFF_W2T   = 9695232;     // 4*8*128*64 bf16 ((e,hc)-chunked)
constexpr size_t OFF_GATES = 10219520;    // chunk*6144 bf16 (adaptive)

// ---------------- kernel 1a: per-node degree count ----------------
__global__ __launch_bounds__(256) void edge_count_kernel(
    const int* __restrict__ edge_index, int* __restrict__ deg)
{
  int e = blockIdx.x * 256 + threadIdx.x;
  int dst = __builtin_nontemporal_load(&edge_index[NEDGES + e]);
  atomicAdd(&deg[dst], 1);
}

// ---------------- kernel 1b: exclusive scan (single block) ----------------
__global__ __launch_bounds__(256) void scan_kernel(
    const int* __restrict__ deg, int* __restrict__ offs, int* __restrict__ cur)
{
  __shared__ int part[256];
  int t = threadIdx.x;
  int s = 0;
  #pragma unroll 4
  for (int i = 0; i < 32; ++i) s += deg[t * 32 + i];
  part[t] = s;
  __syncthreads();
  int incl = s;
  for (int off = 1; off < 256; off <<= 1) {
    int u = (t >= off) ? part[t - off] : 0;
    __syncthreads();
    incl += u;
    part[t] = incl;
    __syncthreads();
  }
  int run = incl - s;      // exclusive prefix of this thread's 32-chunk
  for (int i = 0; i < 32; ++i) {
    int d = deg[t * 32 + i];
    offs[t * 32 + i] = run;
    cur[t * 32 + i]  = run;
    run += d;
  }
  if (t == 255) offs[8192] = run;   // == NEDGES
}

// ---------------- kernel 1c: fill CSR edge-id slots ----------------
__global__ __launch_bounds__(256) void edge_fill_kernel(
    const int* __restrict__ edge_index, int* __restrict__ cur, int* __restrict__ eids)
{
  int e = blockIdx.x * 256 + threadIdx.x;
  int dst = __builtin_nontemporal_load(&edge_index[NEDGES + e]);
  int pos = atomicAdd(&cur[dst], 1);
  eids[pos] = e;
}

// ---------------- kernel 1d: gather + mean + ROUTER (fused) ----------------
// 8-way edge-parallel mean into LDS, then the 2-layer router MLP + softmax
// in the same block (c never leaves LDS; csum buffer eliminated).
__global__ __launch_bounds__(256) void gather_mean_router_kernel(
    const float* __restrict__ t_ij, const int* __restrict__ offs,
    const int* __restrict__ eids,
    const float* __restrict__ r_w1, const float* __restrict__ r_b1,
    const float* __restrict__ r_w2, const float* __restrict__ r_b2,
    bf16_t* __restrict__ cbf, float* __restrict__ wroute)
{
  __shared__ float red[8][128];
  __shared__ float mm[128];
  __shared__ float h1s[128];
  __shared__ float lg[4];
  int n = blockIdx.x, tid = threadIdx.x;
  int sub = tid & 31, rp = tid >> 5;           // 8 groups x 32 lanes (16 B each)
  int o0 = offs[n], o1 = offs[n + 1];
  f32x4 acc = {0.f, 0.f, 0.f, 0.f};
  for (int j = o0 + rp; j < o1; j += 8) {
    int e = __builtin_nontemporal_load(&eids[j]);
    f32x4 v = __builtin_nontemporal_load((const f32x4*)&t_ij[(size_t)e * CCH + sub * 4]);
    #pragma unroll
    for (int q = 0; q < 4; ++q) acc[q] += v[q];
  }
  *(f32x4*)&red[rp][sub * 4] = acc;
  __syncthreads();
  if (rp == 0) {
    float inv = 1.f / fmaxf((float)(o1 - o0), 1.f);
    f32x4 s = {0.f, 0.f, 0.f, 0.f};
    #pragma unroll
    for (int k = 0; k < 8; ++k) {
      f32x4 r = *(const f32x4*)&red[k][sub * 4];
      #pragma unroll
      for (int q = 0; q < 4; ++q) s[q] += r[q];
    }
    f32x4 m;
    bf16x4 mb;
    #pragma unroll
    for (int q = 0; q < 4; ++q) { m[q] = s[q] * inv; mb[q] = (bf16_t)m[q]; }
    *(f32x4*)&mm[sub * 4] = m;
    *(bf16x4*)&cbf[(size_t)n * CCH + sub * 4] = mb;
  }
  __syncthreads();
  // router layer 1: h1 = silu(m @ r_w1 + b1)
  if (tid < 128) {
    float a = r_b1[tid];
    #pragma unroll 8
    for (int k = 0; k < 128; ++k) a += mm[k] * r_w1[k * 128 + tid];
    h1s[tid] = siluf(a);
  }
  __syncthreads();
  // router layer 2 + softmax
  if (tid < 4) {
    float s2 = r_b2[tid];
    for (int j = 0; j < 128; ++j) s2 += h1s[j] * r_w2[j * 4 + tid];
    lg[tid] = s2;
  }
  __syncthreads();
  if (tid == 0) {
    float m = fmaxf(fmaxf(lg[0], lg[1]), fmaxf(lg[2], lg[3]));
    float e0 = __expf(lg[0] - m), e1 = __expf(lg[1] - m);
    float e2 = __expf(lg[2] - m), e3 = __expf(lg[3] - m);
    float s = 1.f / (e0 + e1 + e2 + e3);
    f32x4 w = {e0 * s, e1 * s, e2 * s, e3 * s};
    *(f32x4*)&wroute[n * 4] = w;
  }
}

// ---------------- kernel 3: pack weights via LDS 32x32 tiled transpose ----------------
__global__ __launch_bounds__(256) void pack_kernel(
    const float* __restrict__ eq_gate_w, const float* __restrict__ ne_gate_w,
    const float* __restrict__ eq_gate_b, const float* __restrict__ ne_gate_b,
    const float* __restrict__ eq_w1, const float* __restrict__ ne_w1,
    const float* __restrict__ eq_w2, const float* __restrict__ ne_w2,
    bf16_t* __restrict__ WpackT, float* __restrict__ bpack,
    bf16_t* __restrict__ w1T, bf16_t* __restrict__ w2c)
{
  __shared__ float tb[32][33];
  int b = blockIdx.x;
  int tid = threadIdx.x, tx = tid & 31, ty = tid >> 5;   // 32 x 8
  if (b == 1280) {                                       // biases (contiguous)
    #pragma unroll
    for (int it = 0; it < 24; ++it) {
      int j = it * 256 + tid;
      bpack[j] = (j < 5120) ? eq_gate_b[j] : ne_gate_b[j - 5120];
    }
    return;
  }
  const float* src; bf16_t* dst; int stride; bool w2mode = false;
  int c0, h0; size_t dbase;
  if (b < 640) {                       // WpackT eq: [2][128c][2560h] -> [j=e*2560+h][c]
    int e = b / 320, r = b % 320, ct = r / 80, ht = r % 80;
    src = eq_gate_w + (size_t)e * 327680; stride = 2560;
    c0 = ct * 32; h0 = ht * 32;
    dbase = ((size_t)e * 2560 + h0) * 128 + c0; dst = WpackT;
  } else if (b < 768) {                // WpackT ne: [2][128c][512h] -> [5120+e*512+h][c]
    int bb = b - 640, e = bb / 64, r = bb % 64, ct = r / 16, ht = r % 16;
    src = ne_gate_w + (size_t)e * 65536; stride = 512;
    c0 = ct * 32; h0 = ht * 32;
    dbase = ((size_t)(5120 + e * 512) + h0) * 128 + c0; dst = WpackT;
  } else if (b < 1024) {               // w1T: [e][128c][512h] -> [e*512+h][c]
    int bb = b - 768, e = bb / 64, r = bb % 64, ct = r / 16, ht = r % 16;
    src = (e < 2) ? eq_w1 + (size_t)e * 65536 : ne_w1 + (size_t)(e - 2) * 65536;
    stride = 512;
    c0 = ct * 32; h0 = ht * 32;
    dbase = ((size_t)(e * 512) + h0) * 128 + c0; dst = w1T;
  } else {                             // w2c: [e][512h][128c] -> [e][h>>6][c][h&63]
    int bb = b - 1024, e = bb / 64, r = bb % 64, ht = r / 4, ct = r % 4;
    src = (e < 2) ? eq_w2 + (size_t)e * 65536 : ne_w2 + (size_t)(e - 2) * 65536;
    stride = 128; w2mode = true;
    c0 = ct * 32; h0 = ht * 32;
    dbase = (size_t)e * 65536 + (size_t)(ht >> 1) * 8192 + (size_t)c0 * 64 + (size_t)(ht & 1) * 32;
    dst = w2c;
  }
  if (!w2mode) {
    #pragma unroll
    for (int p = 0; p < 4; ++p)        // tb[c'][h'], coalesced src rows (c-major)
      tb[p * 8 + ty][tx] = src[(size_t)(c0 + p * 8 + ty) * stride + h0 + tx];
    __syncthreads();
    #pragma unroll
    for (int p = 0; p < 4; ++p)        // row h, cols c contiguous
      dst[dbase + (size_t)(p * 8 + ty) * 128 + tx] = (bf16_t)tb[tx][p * 8 + ty];
  } else {
    #pragma unroll
    for (int p = 0; p < 4; ++p)        // tb[h'][c'], coalesced src rows (h-major)
      tb[p * 8 + ty][tx] = src[(size_t)(h0 + p * 8 + ty) * 128 + c0 + tx];
    __syncthreads();
    #pragma unroll
    for (int p = 0; p < 4; ++p)        // row c, cols h contiguous
      dst[dbase + (size_t)(p * 8 + ty) * 64 + tx] = (bf16_t)tb[tx][p * 8 + ty];
  }
}

// ---------------- kernel 5: gate GEMM ----------------
// gates[n][p] = silu(c@Wpack + b) * wroute[n][e(j)], stored PERMUTED within each
// 64-col chunk: logical j = tr*16 + quad*4 + q  ->  p = quad*16 + tr*4 + q.
__global__ __launch_bounds__(256, 2) void gate_gemm_kernel(
    const bf16_t* __restrict__ WpackT, const bf16_t* __restrict__ cbf,
    const float* __restrict__ bpack, const float* __restrict__ wroute,
    bf16_t* __restrict__ gates, int n0)
{
  __shared__ bf16_t gt[128 * XSPAD];
  int jt = blockIdx.x, nt = blockIdx.y;
  int tid = threadIdx.x;
  int wave = tid >> 6, lane = tid & 63;
  int wr = wave >> 1, wc = wave & 1;
  int l15 = lane & 15, quad = lane >> 4;
  int ej = (jt < 20) ? 0 : (jt < 40) ? 1 : (jt < 44) ? 2 : 3;

  f32x4 acc[4][4];
  #pragma unroll
  for (int i = 0; i < 4; ++i)
    #pragma unroll
    for (int j = 0; j < 4; ++j) acc[i][j] = {0.f, 0.f, 0.f, 0.f};

  const bf16_t* abase = WpackT + ((size_t)jt * 128 + wr * 64 + l15) * 128 + quad * 8;
  const bf16_t* bbase = cbf + ((size_t)(n0 + nt * 128) + wc * 64 + l15) * 128 + quad * 8;
  float wsc[4];
  #pragma unroll
  for (int tc = 0; tc < 4; ++tc)
    wsc[tc] = wroute[(size_t)(n0 + nt * 128 + wc * 64 + tc * 16 + l15) * 4 + ej];
  #pragma unroll
  for (int ks = 0; ks < 4; ++ks) {
    bf16x8 af[4], bfr[4];
    #pragma unroll
    for (int tr = 0; tr < 4; ++tr) af[tr] = *(const bf16x8*)(abase + (size_t)tr * 16 * 128 + ks * 32);
    #pragma unroll
    for (int tc = 0; tc < 4; ++tc) bfr[tc] = *(const bf16x8*)(bbase + (size_t)tc * 16 * 128 + ks * 32);
    #pragma unroll
    for (int tr = 0; tr < 4; ++tr)
      #pragma unroll
      for (int tc = 0; tc < 4; ++tc)
        acc[tr][tc] = __builtin_amdgcn_mfma_f32_16x16x32_bf16(af[tr], bfr[tc], acc[tr][tc], 0, 0, 0);
  }
  #pragma unroll
  for (int tr = 0; tr < 4; ++tr) {
    int j0 = wr * 64 + tr * 16 + quad * 4;       // logical col (for bias values)
    int p0 = wr * 64 + quad * 16 + tr * 4;       // permuted store position
    f32x4 bb = *(const f32x4*)&bpack[jt * 128 + j0];
    #pragma unroll
    for (int tc = 0; tc < 4; ++tc) {
      int nl = wc * 64 + tc * 16 + l15;
      f32x4 v = acc[tr][tc];
      bf16x4 gv;
      #pragma unroll
      for (int q = 0; q < 4; ++q) gv[q] = (bf16_t)(siluf(v[q] + bb[q]) * wsc[tc]);
      *(bf16x4*)&gt[nl * XSPAD + p0] = gv;
    }
  }
  __syncthreads();
  #pragma unroll
  for (int it = 0; it < 8; ++it) {
    int idx = it * 2048 + tid * 8;
    int lr = idx >> 7, col = idx & 127;
    *(bf16x8*)&gates[((size_t)nt * 128 + lr) * GCOLS + jt * 128 + col] =
        *(const bf16x8*)&gt[lr * XSPAD + col];
  }
}

// ---------------- kernel 6: fused experts (R4 structure + gating/GEMM2 interleave) ----------------
// R4 (best measured, 431 us) reverted verbatim: 64-h chunks, 32 iters,
// issue-early staging, (256,2), HGPAD-72 hg, LDS 50 KB.
// NEW vs R4: gating is split by GEMM2's K-halves and moved after B1:
//   GEMM1 -> B1 -> stage ws1(t+1) -> gate(h<32) -> GEMM2 ks0
//                                 -> gate(h>=32) -> GEMM2 ks1 -> B2 -> stage ws2(t+1)
// Phase-B gating VALU can now schedule under ks0's MFMA window (no barrier
// between; hg halves are disjoint, same-wave DS is in-order).
__global__ __launch_bounds__(256, 2) void fused_experts_kernel(
    const float* __restrict__ x,       // [204800][128] fp32
    const bf16_t* __restrict__ w1T,    // [4][512][128], (e,hc) chunk = 8192 elems
    const bf16_t* __restrict__ w2c,    // [4][8][128][64], (e,hc) chunk = 8192 elems
    const bf16_t* __restrict__ gates,  // [chunk][6144], pre-scaled, 64-chunk-permuted
    const float* __restrict__ wroute,  // [8192][4]
    const float* __restrict__ ne_b1,   // [2][512] fp32
    const float* __restrict__ ne_b2,   // [2][128] fp32
    float* __restrict__ out,           // [204800][128] fp32
    int n0)
{
  __shared__ __align__(16) bf16_t ws1[8192];          // 16 KB w1 chunk (swizzled)
  __shared__ __align__(16) bf16_t ws2[8192];          // 16 KB w2 chunk (swizzled)
  __shared__ __align__(16) bf16_t hg[4 * 32 * HGPAD]; // 18 KB wave-private

  const int tid = threadIdx.x;
  const int wave = tid >> 6, lane = tid & 63;
  const int l15 = lane & 15, quad = lane >> 4;
  const int r0 = n0 * 25 + blockIdx.x * 128;
  const int rbase = wave * 32;
  bf16_t* hgw = hg + wave * 32 * HGPAD;

  // staging source offsets (bf16 elems): LDS byte p gets source byte
  // row*stride + ((p%stride) ^ ((row&7)<<4))  -> linear-dest swizzled content
  int soff1[4], soff2[4];
  #pragma unroll
  for (int i = 0; i < 4; ++i) {
    int p = wave * 4096 + i * 1024 + lane * 16;
    int row1 = p >> 8;                         // w1: 64 rows x 256 B
    soff1[i] = (row1 * 256 + ((p & 255) ^ ((row1 & 7) << 4))) >> 1;
    int row2 = p >> 7;                         // w2: 128 rows x 128 B
    soff2[i] = (row2 * 128 + ((p & 127) ^ ((row2 & 7) << 4))) >> 1;
  }
  const int swz = (l15 & 7) << 4;              // read-side XOR (row&7 == l15&7)
  int colswz[4];
  #pragma unroll
  for (int ks = 0; ks < 4; ++ks) colswz[ks] = (ks * 64 + quad * 16) ^ swz;

  // per-lane row metadata + x panel into registers (non-temporal: read-once)
  int nloc[2], lidx[2];
  f32x4 rw[2];
  bf16x8 xf[2][4];
  #pragma unroll
  for (int tc = 0; tc < 2; ++tc) {
    int r = r0 + rbase + tc * 16 + l15;
    int n = r / 25;
    int m = r - n * 25;
    nloc[tc] = n - n0;
    lidx[tc] = (m == 0) ? 0 : (m < 4) ? 1 : (m < 9) ? 2 : (m < 16) ? 3 : 4;
    rw[tc] = *(const f32x4*)&wroute[n * 4];
    const float* xr = x + (size_t)r * CCH + quad * 8;
    #pragma unroll
    for (int ks = 0; ks < 4; ++ks) {
      f32x4 a = __builtin_nontemporal_load((const f32x4*)(xr + ks * 32));
      f32x4 b = __builtin_nontemporal_load((const f32x4*)(xr + ks * 32 + 4));
      bf16x8 v;
      #pragma unroll
      for (int q = 0; q < 4; ++q) { v[q] = (bf16_t)a[q]; v[4 + q] = (bf16_t)b[q]; }
      xf[tc][ks] = v;
    }
  }

  // gates address for (tc, iter tt): permuted chunk => lane reads 32 contiguous B
  auto gaddr = [&](int tc, int tt) -> const bf16_t* {
    int ee = tt >> 3, hh = tt & 7;
    int base = (ee < 2) ? ee * 2560 + lidx[tc] * 512 : 5120 + (ee - 2) * 512;
    return gates + (nloc[tc] * GCOLS + base + hh * 64 + quad * 16);
  };

  f32x4 oacc[8][2];
  #pragma unroll
  for (int i = 0; i < 8; ++i)
    #pragma unroll
    for (int j = 0; j < 2; ++j) oacc[i][j] = {0.f, 0.f, 0.f, 0.f};

  // prologue: gates(0) prefetch, then stage chunk 0 (both buffers), one drain
  bf16x8 gnxa[2], gnxb[2];
  #pragma unroll
  for (int tc = 0; tc < 2; ++tc) {
    const bf16_t* gp = gaddr(tc, 0);
    gnxa[tc] = *(const bf16x8*)gp;
    gnxb[tc] = *(const bf16x8*)(gp + 8);
  }
  #pragma unroll
  for (int i = 0; i < 4; ++i) {
    GLOAD_LDS(w1T + soff1[i], ws1 + wave * 2048 + i * 512);
    GLOAD_LDS(w2c + soff2[i], ws2 + wave * 2048 + i * 512);
  }
  __syncthreads();                       // cold drain, once

  #pragma unroll 1
  for (int t = 0; t < 32; ++t) {
    const int e = t >> 3, hc = t & 7;
    const bool is_eq = (e < 2);

    // ---- consume prefetched gates; issue next iter's ----
    bf16x8 ga[2], gb[2];
    #pragma unroll
    for (int tc = 0; tc < 2; ++tc) { ga[tc] = gnxa[tc]; gb[tc] = gnxb[tc]; }
    if (t < 31) {
      #pragma unroll
      for (int tc = 0; tc < 2; ++tc) {
        const bf16_t* gp = gaddr(tc, t + 1);
        gnxa[tc] = *(const bf16x8*)gp;
        gnxb[tc] = *(const bf16x8*)(gp + 8);
      }
    }

    // ---- GEMM1: hacc[h(4x16)][r(2x16)], K=128, A from ws1 ----
    f32x4 hacc[4][2];
    #pragma unroll
    for (int i = 0; i < 4; ++i)
      #pragma unroll
      for (int j = 0; j < 2; ++j) hacc[i][j] = {0.f, 0.f, 0.f, 0.f};
    #pragma unroll
    for (int ks = 0; ks < 4; ++ks) {
      bf16x8 af[4];
      #pragma unroll
      for (int tr = 0; tr < 4; ++tr)
        af[tr] = *(const bf16x8*)((const char*)ws1 + (l15 + tr * 16) * 256 + colswz[ks]);
      #pragma unroll
      for (int tr = 0; tr < 4; ++tr)
        #pragma unroll
        for (int tc = 0; tc < 2; ++tc)
          hacc[tr][tc] = __builtin_amdgcn_mfma_f32_16x16x32_bf16(af[tr], xf[tc][ks], hacc[tr][tc], 0, 0, 0);
    }
    __syncthreads();   // B1: ws1(t) reads done everywhere; ws2(t) drained+visible
    // ---- stage ws1(t+1): flies over gating+GEMM2 ----
    if (t < 31) {
      const bf16_t* g1 = w1T + ((size_t)(t + 1) << 13);
      #pragma unroll
      for (int i = 0; i < 4; ++i)
        GLOAD_LDS(g1 + soff1[i], ws1 + wave * 2048 + i * 512);
    }
    // ---- gating phase A (tr 0,1 -> h<32) + GEMM2 ks0, then phase B + ks1 ----
    #pragma unroll
    for (int half = 0; half < 2; ++half) {
      #pragma unroll
      for (int tc = 0; tc < 2; ++tc) {
        #pragma unroll
        for (int trh = 0; trh < 2; ++trh) {
          int tr = half * 2 + trh;
          int hl = tr * 16 + quad * 4;
          f32x4 v = hacc[tr][tc];
          if (is_eq) {
            if (lidx[tc] == 0) {
              #pragma unroll
              for (int q = 0; q < 4; ++q) v[q] = siluf(v[q]);
            }
          } else {
            f32x4 b1 = *(const f32x4*)&ne_b1[(e - 2) * 512 + hc * 64 + hl];
            #pragma unroll
            for (int q = 0; q < 4; ++q) v[q] = siluf(v[q] + b1[q]);
          }
          bf16x4 hv;
          #pragma unroll
          for (int q = 0; q < 4; ++q) {
            float gf = (float)((half == 0 ? ga[tc] : gb[tc])[trh * 4 + q]);
            hv[q] = (bf16_t)(v[q] * gf);
          }
          *(bf16x4*)&hgw[(tc * 16 + l15) * HGPAD + hl] = hv;
        }
      }
      // GEMM2 K-half `half`: oacc[c(8x16)][r(2x16)] += ws2 * hg
      bf16x8 bfr[2];
      #pragma unroll
      for (int tc = 0; tc < 2; ++tc)
        bfr[tc] = *(const bf16x8*)&hgw[(tc * 16 + l15) * HGPAD + half * 32 + quad * 8];
      #pragma unroll
      for (int tr = 0; tr < 8; ++tr) {
        bf16x8 af2 = *(const bf16x8*)((const char*)ws2 + (l15 + tr * 16) * 128 + colswz[half]);
        #pragma unroll
        for (int tc = 0; tc < 2; ++tc)
          oacc[tr][tc] = __builtin_amdgcn_mfma_f32_16x16x32_bf16(af2, bfr[tc], oacc[tr][tc], 0, 0, 0);
      }
    }
    __syncthreads();   // B2: ws2(t) reads done everywhere; ws1(t+1) drained+visible
    // ---- stage ws2(t+1): flies over gates prefetch + GEMM1 of t+1 ----
    if (t < 31) {
      const bf16_t* g2 = w2c + ((size_t)(t + 1) << 13);
      #pragma unroll
      for (int i = 0; i < 4; ++i)
        GLOAD_LDS(g2 + soff2[i], ws2 + wave * 2048 + i * 512);
    }
  }
  // ---- epilogue: out[r][c] = oacc + w_ne*b2 terms (NT fp32 store) ----
  #pragma unroll
  for (int tc = 0; tc < 2; ++tc) {
    size_t rg = (size_t)(r0 + rbase + tc * 16 + l15);
    float wn0 = rw[tc][2], wn1 = rw[tc][3];
    #pragma unroll
    for (int tr = 0; tr < 8; ++tr) {
      int c0 = tr * 16 + quad * 4;
      f32x4 v = oacc[tr][tc];
      f32x4 b20 = *(const f32x4*)&ne_b2[c0];
      f32x4 b21 = *(const f32x4*)&ne_b2[128 + c0];
      f32x4 ov;
      #pragma unroll
      for (int q = 0; q < 4; ++q)
        ov[q] = v[q] + wn0 * b20[q] + wn1 * b21[q];
      __builtin_nontemporal_store(ov, (f32x4*)&out[rg * CCH + c0]);
    }
  }
}

// ---------------- launch ----------------
extern "C" void kernel_launch(void* const* d_in, const int* in_sizes, int n_in,
                              void* d_out, int out_size, void* d_ws, size_t ws_size,
                              hipStream_t stream)
{
  const float* x_emb     = (const float*)d_in[0];
  const float* t_ij      = (const float*)d_in[1];
  const int*   edge_index= (const int*)d_in[2];
  const float* eq_w1     = (const float*)d_in[3];
  const float* eq_gate_w = (const float*)d_in[4];
  const float* eq_gate_b = (const float*)d_in[5];
  const float* eq_w2     = (const float*)d_in[6];
  const float* ne_w1     = (const float*)d_in[7];
  const float* ne_b1     = (const float*)d_in[8];
  const float* ne_gate_w = (const float*)d_in[9];
  const float* ne_gate_b = (const float*)d_in[10];
  const float* ne_w2     = (const float*)d_in[11];
  const float* ne_b2     = (const float*)d_in[12];
  const float* r_w1      = (const float*)d_in[13];
  const float* r_b1      = (const float*)d_in[14];
  const float* r_w2      = (const float*)d_in[15];
  const float* r_b2      = (const float*)d_in[16];
  float* out = (float*)d_out;

  char* ws = (char*)d_ws;
  int*    deg    = (int*)(ws + OFF_DEG);
  int*    offs   = (int*)(ws + OFF_OFFS);
  int*    cur    = (int*)(ws + OFF_CUR);
  int*    eids   = (int*)(ws + OFF_EIDS);
  float*  wroute = (float*)(ws + OFF_WRT);
  bf16_t* cbf    = (bf16_t*)(ws + OFF_CBF);
  bf16_t* WpackT = (bf16_t*)(ws + OFF_WPT);
  float*  bpack  = (float*)(ws + OFF_BPK);
  bf16_t* w1T    = (bf16_t*)(ws + OFF_W1T);
  bf16_t* w2c    = (bf16_t*)(ws + OFF_W2T);
  bf16_t* gates  = (bf16_t*)(ws + OFF_GATES);

  // Adaptive node-chunking for the gates buffer (ws_size constant across calls).
  size_t avail = (ws_size > OFF_GATES) ? ws_size - OFF_GATES : 0;
  int chunk = 128;
  for (int c = NNODES; c >= 128; c >>= 1) {
    if ((size_t)c * GCOLS * sizeof(bf16_t) <= avail) { chunk = c; break; }
  }

  hipMemsetAsync(ws + OFF_DEG, 0, 32768, stream);   // zero deg only

  // CSR build + gather-mean (+fused router)
  edge_count_kernel<<<NEDGES / 256, 256, 0, stream>>>(edge_index, deg);
  scan_kernel<<<1, 256, 0, stream>>>(deg, offs, cur);
  edge_fill_kernel<<<NEDGES / 256, 256, 0, stream>>>(edge_index, cur, eids);
  gather_mean_router_kernel<<<NNODES, 256, 0, stream>>>(
      t_ij, offs, eids, r_w1, r_b1, r_w2, r_b2, cbf, wroute);

  pack_kernel<<<1281, 256, 0, stream>>>(eq_gate_w, ne_gate_w, eq_gate_b, ne_gate_b,
                                        eq_w1, ne_w1, eq_w2, ne_w2,
                                        WpackT, bpack, w1T, w2c);

  for (int n0 = 0; n0 < NNODES; n0 += chunk) {
    gate_gemm_kernel<<<dim3(GCOLS / 128, chunk / 128), 256, 0, stream>>>(
        WpackT, cbf, bpack, wroute, gates, n0);
    fused_experts_kernel<<<chunk * 25 / 128, 256, 0, stream>>>(
        x_emb, w1T, w2c, gates, wroute, ne_b1, ne_b2, out, n0);
  }
}